// Round 2
// 560.660 us; speedup vs baseline: 1.6709x; 1.6709x over previous
//
#include <hip/hip_runtime.h>
#include <hip/hip_bf16.h>

typedef __hip_bfloat16 bf16;
typedef __attribute__((ext_vector_type(8))) short bf16x8;
typedef __attribute__((ext_vector_type(4))) float f32x4;

#define NB 8
#define NC 256
#define ND 32
#define NH 8
#define NN 16384
#define TILE_P 32

#define MFMA16(a, b, c) __builtin_amdgcn_mfma_f32_16x16x32_bf16((a), (b), (c), 0, 0, 0)

__device__ __forceinline__ float u2f(unsigned short u) {
  union { unsigned int i; float f; } v; v.i = ((unsigned int)u) << 16; return v.f;
}
__device__ __forceinline__ unsigned short f2u(float f) {
  union { float f; unsigned int i; } v; v.f = f;
  unsigned int x = v.i;
  return (unsigned short)((x + 0x7fffu + ((x >> 16) & 1u)) >> 16);  // RNE
}
__device__ __forceinline__ float ldg(const void* p, size_t i, int isbf) {
  return isbf ? u2f(((const unsigned short*)p)[i]) : ((const float*)p)[i];
}

// ---------------- dtype detect: low-16 exponent-field statistics ----------------
__global__ __launch_bounds__(256) void detect_kernel(const void* __restrict__ x,
                                                     int* __restrict__ flag) {
  __shared__ int red[4];
  const unsigned int* w = (const unsigned int*)x;
  int cnt = 0;
  for (int i = threadIdx.x; i < 4096; i += 256) {
    unsigned int e = (w[i] >> 7) & 0xFFu;
    cnt += (e >= 100u && e <= 135u) ? 1 : 0;
  }
  for (int off = 32; off; off >>= 1) cnt += __shfl_xor(cnt, off, 64);
  if ((threadIdx.x & 63) == 0) red[threadIdx.x >> 6] = cnt;
  __syncthreads();
  if (threadIdx.x == 0)
    flag[0] = (red[0] + red[1] + red[2] + red[3] > 2048) ? 1 : 0;
}

// ---------------- prep: pack W into per-lane MFMA A-fragment layout ----------------
// slot = (kt*16 + mb)*64 + lane ; lane holds W[o = mb*16+(lane&15)][k = kt*32+8*(lane>>4)+e]
// hi/lo double-bf16 split (lo = 0 in bf16 mode).
// 16384 threads total: 2 matrices x 128 (kt*16+mb) x 64 lanes.
__global__ __launch_bounds__(256) void prep_weights(
    const void* __restrict__ wq, const void* __restrict__ wp,
    const int* __restrict__ flag,
    unsigned short* __restrict__ WqPh, unsigned short* __restrict__ WqPl,
    unsigned short* __restrict__ WpPh, unsigned short* __restrict__ WpPl) {
  int isbf = flag[0];
  int idx = blockIdx.x * 256 + threadIdx.x;  // 16384 total
  int mat = idx >> 13;                       // 0: wq, 1: wp
  int slot = idx & 8191;                     // [0, 8192)
  int lane = slot & 63;
  int mbkt = slot >> 6;                      // [0, 128)
  int mb = mbkt & 15, kt = mbkt >> 4;        // mb [0,16), kt [0,8)
  int o = mb * 16 + (lane & 15);
  int k0 = kt * 32 + (lane >> 4) * 8;
  const void* w = mat ? wp : wq;
  unsigned short* Ph = mat ? WpPh : WqPh;
  unsigned short* Pl = mat ? WpPl : WqPl;
  unsigned short h[8], lo[8];
#pragma unroll
  for (int e = 0; e < 8; e++) {
    float v = ldg(w, (size_t)o * NC + k0 + e, isbf);
    unsigned short hh = f2u(v);
    h[e] = hh;
    lo[e] = isbf ? (unsigned short)0 : f2u(v - u2f(hh));
  }
  uint4 ph, pl;
  ph.x = h[0] | ((unsigned)h[1] << 16);
  ph.y = h[2] | ((unsigned)h[3] << 16);
  ph.z = h[4] | ((unsigned)h[5] << 16);
  ph.w = h[6] | ((unsigned)h[7] << 16);
  pl.x = lo[0] | ((unsigned)lo[1] << 16);
  pl.y = lo[2] | ((unsigned)lo[3] << 16);
  pl.z = lo[4] | ((unsigned)lo[5] << 16);
  pl.w = lo[6] | ((unsigned)lo[7] << 16);
  *(uint4*)(Ph + (size_t)slot * 8) = ph;
  *(uint4*)(Pl + (size_t)slot * 8) = pl;
}

// ---------------- kv = affine(Wkv @ X) : [B][32][N] fp32 (unchanged) ----------------
#define KV_ACC(X0, X1)                                                  \
  do {                                                                  \
    const float4* wr = (const float4*)&wl[c][0];                        \
    _Pragma("unroll") for (int k = 0; k < 8; k++) {                     \
      float4 w4 = wr[k];                                                \
      acc0[4 * k + 0] += w4.x * (X0); acc1[4 * k + 0] += w4.x * (X1);   \
      acc0[4 * k + 1] += w4.y * (X0); acc1[4 * k + 1] += w4.y * (X1);   \
      acc0[4 * k + 2] += w4.z * (X0); acc1[4 * k + 2] += w4.z * (X1);   \
      acc0[4 * k + 3] += w4.w * (X0); acc1[4 * k + 3] += w4.w * (X1);   \
    }                                                                   \
  } while (0)

__global__ __launch_bounds__(256, 2) void kv_kernel(
    const void* __restrict__ x, const void* __restrict__ wkv,
    const void* __restrict__ kv_scale, const void* __restrict__ kv_bias,
    const int* __restrict__ flag, float* __restrict__ kv_out) {
  __shared__ float wl[NC][ND];
  int isbf = flag[0];
  int tid = threadIdx.x;
  int b = blockIdx.x >> 5;
  int n0 = (blockIdx.x & 31) * 512;
  {
    int d = tid >> 3, cb = (tid & 7) * 32;
    float s = ldg(kv_scale, d, isbf);
    for (int i = 0; i < 32; i++)
      wl[cb + i][d] = ldg(wkv, d * NC + cb + i, isbf) * s;
  }
  __syncthreads();
  float acc0[ND], acc1[ND];
#pragma unroll
  for (int d = 0; d < ND; d++) { acc0[d] = 0.f; acc1[d] = 0.f; }
  size_t base = (size_t)b * NC * NN + n0 + tid * 2;
  if (isbf) {
    const unsigned short* xp = (const unsigned short*)x + base;
    for (int c = 0; c < NC; c++) {
      unsigned int u = *(const unsigned int*)(xp + (size_t)c * NN);
      float x0 = u2f((unsigned short)(u & 0xffffu));
      float x1 = u2f((unsigned short)(u >> 16));
      KV_ACC(x0, x1);
    }
  } else {
    const float* xp = (const float*)x + base;
    for (int c = 0; c < NC; c++) {
      float2 v = *(const float2*)(xp + (size_t)c * NN);
      KV_ACC(v.x, v.y);
    }
  }
  int n = n0 + tid * 2;
#pragma unroll
  for (int d = 0; d < ND; d++) {
    float bias = ldg(kv_bias, d, isbf);
    float2 v = make_float2(acc0[d] + bias, acc1[d] + bias);
    *(float2*)(kv_out + ((size_t)(b * ND + d)) * NN + n) = v;
  }
}

// ---------------- rowmax over N per (b,d) (unchanged) ----------------
__global__ __launch_bounds__(256) void rowmax_kernel(const float* __restrict__ kv,
                                                     float* __restrict__ m) {
  __shared__ float red[4];
  int row = blockIdx.x;
  const float* p = kv + (size_t)row * NN;
  float mx = -3.0e38f;
  for (int i = threadIdx.x; i < NN; i += 256) mx = fmaxf(mx, p[i]);
  for (int off = 32; off; off >>= 1) mx = fmaxf(mx, __shfl_xor(mx, off, 64));
  if ((threadIdx.x & 63) == 0) red[threadIdx.x >> 6] = mx;
  __syncthreads();
  if (threadIdx.x == 0)
    m[row] = fmaxf(fmaxf(red[0], red[1]), fmaxf(red[2], red[3]));
}

// ---------------- partial S,Z (unchanged) ----------------
__global__ __launch_bounds__(256) void ctx_partial(const float* __restrict__ kv,
                                                   const float* __restrict__ m,
                                                   float* __restrict__ S,
                                                   float* __restrict__ Z) {
  __shared__ float kvt[ND][257];
  __shared__ float et[ND][257];
  int b = blockIdx.x >> 6;
  int n0 = (blockIdx.x & 63) * 256;
  int tid = threadIdx.x;
  for (int r = 0; r < ND; r++) {
    float v = kv[((size_t)(b * ND + r)) * NN + n0 + tid];
    kvt[r][tid] = v;
    et[r][tid] = __expf(v - m[b * ND + r]);
  }
  __syncthreads();
  int e = tid & 31, dq = tid >> 5;
  float acc[4] = {0.f, 0.f, 0.f, 0.f};
  for (int n = 0; n < 256; n++) {
    float kve = kvt[e][n];
#pragma unroll
    for (int k = 0; k < 4; k++) acc[k] += et[4 * dq + k][n] * kve;
  }
#pragma unroll
  for (int k = 0; k < 4; k++)
    atomicAdd(&S[((size_t)b * ND + 4 * dq + k) * ND + e], acc[k]);
  if (tid < ND) {
    float z = 0.f;
    for (int n = 0; n < 256; n++) z += et[tid][n];
    atomicAdd(&Z[b * ND + tid], z);
  }
}

__global__ __launch_bounds__(256) void ctx_finalize(const float* __restrict__ S,
                                                    const float* __restrict__ Z,
                                                    float* __restrict__ ctx) {
  int i = blockIdx.x * 256 + threadIdx.x;
  ctx[i] = S[i] / Z[i >> 5];
}

// ---------------- fused MFMA kernel ----------------
// LDS pool layout (byte offsets), bf16 tiles are [32 rows(p)][256 cols] swizzled:
#define XT_OFF 0
#define XTL_OFF 16384
#define SMH_OFF 32768
#define SML_OFF 49152
#define YTH_OFF 0
#define YTL_OFF 16384
#define OT_OFF 32768

__device__ __forceinline__ char* lds_at(char* base, int p, int colb) {
  return base + (p << 9) + (colb ^ ((p & 7) << 4));
}

__global__ __launch_bounds__(256, 2) void fused_main(
    const void* __restrict__ x,
    const unsigned short* __restrict__ WqPh, const unsigned short* __restrict__ WqPl,
    const unsigned short* __restrict__ WpPh, const unsigned short* __restrict__ WpPl,
    const void* __restrict__ q_scale, const void* __restrict__ q_bias,
    const void* __restrict__ p_scale, const void* __restrict__ p_bias,
    const float* __restrict__ ctx, const int* __restrict__ flag,
    void* __restrict__ out) {
  __shared__ __align__(16) char pool[69632];
  __shared__ float qs_l[NC], qb_l[NC], ps_l[NC], pb_l[NC];
  const int isbf = flag[0];
  const int tid = threadIdx.x;
  const int b = blockIdx.x >> 9;
  const int n0 = (blockIdx.x & 511) * TILE_P;
  const int w = tid >> 6;
  const int l = tid & 63;
  const int g = l >> 4;
  const int cc = l & 15;
  const f32x4 zero4 = {0.f, 0.f, 0.f, 0.f};

  qs_l[tid] = ldg(q_scale, tid, isbf);
  qb_l[tid] = ldg(q_bias, tid, isbf);
  ps_l[tid] = ldg(p_scale, tid, isbf);
  pb_l[tid] = ldg(p_bias, tid, isbf);

  // ctx A-fragments (shared by both heads of this wave): A[m=e][k=d] = ctx[d][e]
  bf16x8 cAh[2], cAl[2];
  {
    const float* cb = ctx + (size_t)b * ND * ND;
#pragma unroll
    for (int mp = 0; mp < 2; mp++) {
      bf16x8 ah, al;
#pragma unroll
      for (int el = 0; el < 8; el++) {
        float v = cb[(8 * g + el) * ND + 16 * mp + cc];
        unsigned short hh = f2u(v);
        ah[el] = (short)hh;
        al[el] = (short)f2u(v - u2f(hh));
      }
      cAh[mp] = ah; cAl[mp] = al;
    }
  }

  // ---- stage X tile: transpose to XT[p][c] bf16 (hi, and lo in fp32 mode) ----
  {
    const int c0 = (tid >> 3) * 8;   // 8 consecutive channels
    const int pq = (tid & 7) * 4;    // 4 consecutive pixels
    unsigned short hi[8][4], lo[8][4];
    if (isbf) {
      const unsigned short* xp =
          (const unsigned short*)x + ((size_t)(b * NC + c0)) * NN + n0 + pq;
#pragma unroll
      for (int i = 0; i < 8; i++) {
        ushort4 r = *(const ushort4*)(xp + (size_t)i * NN);
        hi[i][0] = r.x; hi[i][1] = r.y; hi[i][2] = r.z; hi[i][3] = r.w;
      }
    } else {
      const float* xp = (const float*)x + ((size_t)(b * NC + c0)) * NN + n0 + pq;
#pragma unroll
      for (int i = 0; i < 8; i++) {
        float4 v = *(const float4*)(xp + (size_t)i * NN);
        float vv[4] = {v.x, v.y, v.z, v.w};
#pragma unroll
        for (int j = 0; j < 4; j++) {
          unsigned short hh = f2u(vv[j]);
          hi[i][j] = hh;
          lo[i][j] = f2u(vv[j] - u2f(hh));
        }
      }
    }
#pragma unroll
    for (int j = 0; j < 4; j++) {
      int p = pq + j;
      uint4 wv;
      wv.x = hi[0][j] | ((unsigned)hi[1][j] << 16);
      wv.y = hi[2][j] | ((unsigned)hi[3][j] << 16);
      wv.z = hi[4][j] | ((unsigned)hi[5][j] << 16);
      wv.w = hi[6][j] | ((unsigned)hi[7][j] << 16);
      *(uint4*)lds_at(pool + XT_OFF, p, c0 * 2) = wv;
      if (!isbf) {
        uint4 wl2;
        wl2.x = lo[0][j] | ((unsigned)lo[1][j] << 16);
        wl2.y = lo[2][j] | ((unsigned)lo[3][j] << 16);
        wl2.z = lo[4][j] | ((unsigned)lo[5][j] << 16);
        wl2.w = lo[6][j] | ((unsigned)lo[7][j] << 16);
        *(uint4*)lds_at(pool + XTL_OFF, p, c0 * 2) = wl2;
      }
    }
  }
  __syncthreads();

  // ---- GEMM1: q = Wq @ x  (wave w -> q channels [64w, 64w+64), 32 pixels) ----
  f32x4 acc[4][2];
#pragma unroll
  for (int mi = 0; mi < 4; mi++) { acc[mi][0] = zero4; acc[mi][1] = zero4; }
  {
    const bf16x8* Aq = (const bf16x8*)WqPh;
    const bf16x8* Aql = (const bf16x8*)WqPl;
#pragma unroll
    for (int kt = 0; kt < 8; kt++) {
      bf16x8 xb0 = *(const bf16x8*)lds_at(pool + XT_OFF, cc, kt * 64 + 16 * g);
      bf16x8 xb1 = *(const bf16x8*)lds_at(pool + XT_OFF, 16 + cc, kt * 64 + 16 * g);
      bf16x8 av[4];
#pragma unroll
      for (int mi = 0; mi < 4; mi++) av[mi] = Aq[(kt * 16 + w * 4 + mi) * 64 + l];
#pragma unroll
      for (int mi = 0; mi < 4; mi++) {
        acc[mi][0] = MFMA16(av[mi], xb0, acc[mi][0]);
        acc[mi][1] = MFMA16(av[mi], xb1, acc[mi][1]);
      }
      if (!isbf) {
        bf16x8 xl0 = *(const bf16x8*)lds_at(pool + XTL_OFF, cc, kt * 64 + 16 * g);
        bf16x8 xl1 = *(const bf16x8*)lds_at(pool + XTL_OFF, 16 + cc, kt * 64 + 16 * g);
#pragma unroll
        for (int mi = 0; mi < 4; mi++) {
          bf16x8 al2 = Aql[(kt * 16 + w * 4 + mi) * 64 + l];
          acc[mi][0] = MFMA16(av[mi], xl0, acc[mi][0]);
          acc[mi][1] = MFMA16(av[mi], xl1, acc[mi][1]);
          acc[mi][0] = MFMA16(al2, xb0, acc[mi][0]);
          acc[mi][1] = MFMA16(al2, xb1, acc[mi][1]);
          acc[mi][0] = MFMA16(al2, xl0, acc[mi][0]);
          acc[mi][1] = MFMA16(al2, xl1, acc[mi][1]);
        }
      }
    }
  }

  // ---- softmax over D per (head,pixel); E = exp(q - m), hi/lo to SM tiles ----
  float inv_s[2][2];
#pragma unroll
  for (int hp = 0; hp < 2; hp++) {
#pragma unroll
    for (int ni = 0; ni < 2; ni++) {
      float e8[8];
      float mx = -3.0e38f;
#pragma unroll
      for (int mi2 = 0; mi2 < 2; mi2++) {
#pragma unroll
        for (int r = 0; r < 4; r++) {
          int o = w * 64 + (2 * hp + mi2) * 16 + 4 * g + r;
          float v = acc[2 * hp + mi2][ni][r] * qs_l[o] + qb_l[o];
          e8[mi2 * 4 + r] = v;
          mx = fmaxf(mx, v);
        }
      }
      mx = fmaxf(mx, __shfl_xor(mx, 16, 64));
      mx = fmaxf(mx, __shfl_xor(mx, 32, 64));
      float s = 0.f;
#pragma unroll
      for (int i2 = 0; i2 < 8; i2++) { e8[i2] = __expf(e8[i2] - mx); s += e8[i2]; }
      s += __shfl_xor(s, 16, 64);
      s += __shfl_xor(s, 32, 64);
      inv_s[hp][ni] = 1.f / s;
      int p = ni * 16 + cc;
#pragma unroll
      for (int mi2 = 0; mi2 < 2; mi2++) {
        int colb = (w * 64 + (2 * hp + mi2) * 16 + 4 * g) * 2;
        unsigned short h[4], lo2[4];
#pragma unroll
        for (int r = 0; r < 4; r++) {
          float ev = e8[mi2 * 4 + r];
          unsigned short hh = f2u(ev);
          h[r] = hh;
          lo2[r] = f2u(ev - u2f(hh));
        }
        uint2 wh, wl2;
        wh.x = h[0] | ((unsigned)h[1] << 16);
        wh.y = h[2] | ((unsigned)h[3] << 16);
        wl2.x = lo2[0] | ((unsigned)lo2[1] << 16);
        wl2.y = lo2[2] | ((unsigned)lo2[3] << 16);
        *(uint2*)lds_at(pool + SMH_OFF, p, colb) = wh;
        *(uint2*)lds_at(pool + SML_OFF, p, colb) = wl2;
      }
    }
  }
  __syncthreads();  // (1) all XT reads done; SM tiles complete

  // ---- ctx GEMM: att = ctx^T @ E, then /s, relu, hi/lo -> YT tiles ----
#pragma unroll
  for (int hp = 0; hp < 2; hp++) {
    f32x4 cacc[2][2];
#pragma unroll
    for (int mp = 0; mp < 2; mp++) { cacc[mp][0] = zero4; cacc[mp][1] = zero4; }
#pragma unroll
    for (int ni = 0; ni < 2; ni++) {
      int p = ni * 16 + cc;
      int colb = ((2 * w + hp) * 32 + 8 * g) * 2;
      bf16x8 bh = *(const bf16x8*)lds_at(pool + SMH_OFF, p, colb);
      bf16x8 bl = *(const bf16x8*)lds_at(pool + SML_OFF, p, colb);
#pragma unroll
      for (int mp = 0; mp < 2; mp++) {
        cacc[mp][ni] = MFMA16(cAh[mp], bh, cacc[mp][ni]);
        cacc[mp][ni] = MFMA16(cAh[mp], bl, cacc[mp][ni]);
        cacc[mp][ni] = MFMA16(cAl[mp], bh, cacc[mp][ni]);
        if (!isbf) cacc[mp][ni] = MFMA16(cAl[mp], bl, cacc[mp][ni]);
      }
    }
#pragma unroll
    for (int mp = 0; mp < 2; mp++) {
#pragma unroll
      for (int ni = 0; ni < 2; ni++) {
        int p = ni * 16 + cc;
        float iv = inv_s[hp][ni];
        unsigned short h[4], lo2[4];
#pragma unroll
        for (int r = 0; r < 4; r++) {
          float y = fmaxf(cacc[mp][ni][r] * iv, 0.f);
          unsigned short hh = f2u(y);
          h[r] = hh;
          lo2[r] = f2u(y - u2f(hh));
        }
        int colb = ((2 * w + hp) * 32 + mp * 16 + 4 * g) * 2;
        uint2 wh, wl2;
        wh.x = h[0] | ((unsigned)h[1] << 16);
        wh.y = h[2] | ((unsigned)h[3] << 16);
        wl2.x = lo2[0] | ((unsigned)lo2[1] << 16);
        wl2.y = lo2[2] | ((unsigned)lo2[3] << 16);
        *(uint2*)lds_at(pool + YTH_OFF, p, colb) = wh;
        *(uint2*)lds_at(pool + YTL_OFF, p, colb) = wl2;
      }
    }
  }
  __syncthreads();  // (2) YT tiles complete

  // ---- GEMM2: out = Wp @ relu(att) ----
  f32x4 oacc[4][2];
#pragma unroll
  for (int mi = 0; mi < 4; mi++) { oacc[mi][0] = zero4; oacc[mi][1] = zero4; }
  {
    const bf16x8* Ap = (const bf16x8*)WpPh;
    const bf16x8* Apl = (const bf16x8*)WpPl;
#pragma unroll
    for (int kt = 0; kt < 8; kt++) {
      bf16x8 yh0 = *(const bf16x8*)lds_at(pool + YTH_OFF, cc, kt * 64 + 16 * g);
      bf16x8 yh1 = *(const bf16x8*)lds_at(pool + YTH_OFF, 16 + cc, kt * 64 + 16 * g);
      bf16x8 yl0 = *(const bf16x8*)lds_at(pool + YTL_OFF, cc, kt * 64 + 16 * g);
      bf16x8 yl1 = *(const bf16x8*)lds_at(pool + YTL_OFF, 16 + cc, kt * 64 + 16 * g);
      bf16x8 av[4];
#pragma unroll
      for (int mi = 0; mi < 4; mi++) av[mi] = Ap[(kt * 16 + w * 4 + mi) * 64 + l];
#pragma unroll
      for (int mi = 0; mi < 4; mi++) {
        oacc[mi][0] = MFMA16(av[mi], yh0, oacc[mi][0]);
        oacc[mi][1] = MFMA16(av[mi], yh1, oacc[mi][1]);
        oacc[mi][0] = MFMA16(av[mi], yl0, oacc[mi][0]);
        oacc[mi][1] = MFMA16(av[mi], yl1, oacc[mi][1]);
      }
      if (!isbf) {
#pragma unroll
        for (int mi = 0; mi < 4; mi++) {
          bf16x8 al2 = Apl[(kt * 16 + w * 4 + mi) * 64 + l];
          oacc[mi][0] = MFMA16(al2, yh0, oacc[mi][0]);
          oacc[mi][1] = MFMA16(al2, yh1, oacc[mi][1]);
        }
      }
    }
  }

  // ---- epilogue: affine -> OT (channel-major) -> coalesced global store ----
  {
    char* OT = pool + OT_OFF;
#pragma unroll
    for (int mi = 0; mi < 4; mi++) {
#pragma unroll
      for (int ni = 0; ni < 2; ni++) {
#pragma unroll
        for (int r = 0; r < 4; r++) {
          int o = w * 64 + mi * 16 + 4 * g + r;
          float v = oacc[mi][ni][r] * ps_l[o] + pb_l[o];
          int p = ni * 16 + cc;
          if (isbf)
            *(unsigned short*)(OT + o * 80 + p * 2) = f2u(v);
          else
            *(float*)(OT + o * 144 + p * 4) = v;
        }
      }
    }
  }
  __syncthreads();  // (3) OT complete
  {
    char* OT = pool + OT_OFF;
    int o = tid;
    size_t gbase = ((size_t)(b * NC + o)) * NN + n0;
    if (isbf) {
      unsigned short* po = (unsigned short*)out + gbase;
#pragma unroll
      for (int k = 0; k < 4; k++)
        *(uint4*)(po + k * 8) = *(const uint4*)(OT + o * 80 + k * 16);
    } else {
      float* po = (float*)out + gbase;
#pragma unroll
      for (int k = 0; k < 8; k++)
        *(float4*)(po + k * 4) = *(const float4*)(OT + o * 144 + k * 16);
    }
  }
}

extern "C" void kernel_launch(void* const* d_in, const int* in_sizes, int n_in,
                              void* d_out, int out_size, void* d_ws, size_t ws_size,
                              hipStream_t stream) {
  const void* input   = d_in[0];
  const void* wq      = d_in[1];
  const void* q_scale = d_in[2];
  const void* q_bias  = d_in[3];
  const void* wkv     = d_in[4];
  const void* kv_scale= d_in[5];
  const void* kv_bias = d_in[6];
  const void* wp      = d_in[7];
  const void* p_scale = d_in[8];
  const void* p_bias  = d_in[9];

  char* w = (char*)d_ws;
  int*  flag = (int*)w;     w += 256;
  float* kv   = (float*)w;  w += (size_t)NB * ND * NN * 4;   // 16 MiB
  float* mrow = (float*)w;  w += 256 * 4;
  float* S    = (float*)w;  // S then Z contiguous for one memset
  float* Z    = (float*)(w + (size_t)NB * ND * ND * 4);
  w += (size_t)NB * ND * ND * 4 + NB * ND * 4;
  float* ctx  = (float*)w;  w += (size_t)NB * ND * ND * 4;
  unsigned short* WqPh = (unsigned short*)w; w += (size_t)NC * NC * 2;
  unsigned short* WqPl = (unsigned short*)w; w += (size_t)NC * NC * 2;
  unsigned short* WpPh = (unsigned short*)w; w += (size_t)NC * NC * 2;
  unsigned short* WpPl = (unsigned short*)w; w += (size_t)NC * NC * 2;

  hipMemsetAsync(S, 0, (size_t)NB * ND * ND * 4 + NB * ND * 4, stream);
  detect_kernel<<<1, 256, 0, stream>>>(input, flag);
  prep_weights<<<64, 256, 0, stream>>>(wq, wp, flag, WqPh, WqPl, WpPh, WpPl);
  kv_kernel<<<256, 256, 0, stream>>>(input, wkv, kv_scale, kv_bias, flag, kv);
  rowmax_kernel<<<256, 256, 0, stream>>>(kv, mrow);
  ctx_partial<<<512, 256, 0, stream>>>(kv, mrow, S, Z);
  ctx_finalize<<<32, 256, 0, stream>>>(S, Z, ctx);
  fused_main<<<4096, 256, 0, stream>>>(input, WqPh, WqPl, WpPh, WpPl,
                                       q_scale, q_bias, p_scale, p_bias,
                                       ctx, flag, (void*)d_out);
}

// Round 3
// 420.439 us; speedup vs baseline: 2.2282x; 1.3335x over previous
//
#include <hip/hip_runtime.h>
#include <hip/hip_bf16.h>

typedef __hip_bfloat16 bf16;
typedef __attribute__((ext_vector_type(8))) short bf16x8;
typedef __attribute__((ext_vector_type(4))) float f32x4;

#define NB 8
#define NC 256
#define ND 32
#define NH 8
#define NN 16384
#define TILE_P 32

#define MFMA16(a, b, c) __builtin_amdgcn_mfma_f32_16x16x32_bf16((a), (b), (c), 0, 0, 0)

__device__ __forceinline__ float u2f(unsigned short u) {
  union { unsigned int i; float f; } v; v.i = ((unsigned int)u) << 16; return v.f;
}
__device__ __forceinline__ unsigned short f2u(float f) {
  union { float f; unsigned int i; } v; v.f = f;
  unsigned int x = v.i;
  return (unsigned short)((x + 0x7fffu + ((x >> 16) & 1u)) >> 16);  // RNE
}
__device__ __forceinline__ float ldg(const void* p, size_t i, int isbf) {
  return isbf ? u2f(((const unsigned short*)p)[i]) : ((const float*)p)[i];
}
// swizzled LDS addressing: row p (512B rows), byte col colb, 16B-block XOR swizzle
__device__ __forceinline__ char* lds_at(char* base, int p, int colb) {
  return base + (p << 9) + (colb ^ ((p & 7) << 4));
}

// ---------------- dtype detect ----------------
__global__ __launch_bounds__(256) void detect_kernel(const void* __restrict__ x,
                                                     int* __restrict__ flag) {
  __shared__ int red[4];
  const unsigned int* w = (const unsigned int*)x;
  int cnt = 0;
  for (int i = threadIdx.x; i < 4096; i += 256) {
    unsigned int e = (w[i] >> 7) & 0xFFu;
    cnt += (e >= 100u && e <= 135u) ? 1 : 0;
  }
  for (int off = 32; off; off >>= 1) cnt += __shfl_xor(cnt, off, 64);
  if ((threadIdx.x & 63) == 0) red[threadIdx.x >> 6] = cnt;
  __syncthreads();
  if (threadIdx.x == 0)
    flag[0] = (red[0] + red[1] + red[2] + red[3] > 2048) ? 1 : 0;
}

// ---------------- prep: pack Wq/Wp/Wkv into per-lane MFMA A-fragment layout ----------------
// slot = (kt*NMB + mb)*64 + lane ; lane holds W[o = mb*16+(lane&15)][k = kt*32+8*(lane>>4)+e]
// hi/lo double-bf16 split (lo = 0 in bf16 mode).
__global__ __launch_bounds__(256) void prep_weights(
    const void* __restrict__ wq, const void* __restrict__ wp,
    const void* __restrict__ wkv, const int* __restrict__ flag,
    unsigned short* __restrict__ WqPh, unsigned short* __restrict__ WqPl,
    unsigned short* __restrict__ WpPh, unsigned short* __restrict__ WpPl,
    unsigned short* __restrict__ WkPh, unsigned short* __restrict__ WkPl) {
  int isbf = flag[0];
  int idx = blockIdx.x * 256 + threadIdx.x;  // 17408 total
  const void* w;
  unsigned short *Ph, *Pl;
  int slot, o, k0;
  if (idx < 16384) {
    int mat = idx >> 13;       // 0: wq, 1: wp
    slot = idx & 8191;         // [0, 8192)
    int lane = slot & 63;
    int mbkt = slot >> 6;      // [0, 128)
    int mb = mbkt & 15, kt = mbkt >> 4;  // mb [0,16), kt [0,8)
    o = mb * 16 + (lane & 15);
    k0 = kt * 32 + (lane >> 4) * 8;
    w = mat ? wp : wq;
    Ph = mat ? WpPh : WqPh;
    Pl = mat ? WpPl : WqPl;
  } else {
    slot = idx - 16384;        // [0, 1024)
    int lane = slot & 63;
    int grp = slot >> 6;       // [0,16) = kt*2 + mb
    int mb = grp & 1, kt = grp >> 1;
    o = mb * 16 + (lane & 15);           // [0,32)
    k0 = kt * 32 + (lane >> 4) * 8;
    w = wkv;
    Ph = WkPh;
    Pl = WkPl;
  }
  unsigned short h[8], lo[8];
#pragma unroll
  for (int e = 0; e < 8; e++) {
    float v = ldg(w, (size_t)o * NC + k0 + e, isbf);
    unsigned short hh = f2u(v);
    h[e] = hh;
    lo[e] = isbf ? (unsigned short)0 : f2u(v - u2f(hh));
  }
  uint4 ph, pl;
  ph.x = h[0] | ((unsigned)h[1] << 16);
  ph.y = h[2] | ((unsigned)h[3] << 16);
  ph.z = h[4] | ((unsigned)h[5] << 16);
  ph.w = h[6] | ((unsigned)h[7] << 16);
  pl.x = lo[0] | ((unsigned)lo[1] << 16);
  pl.y = lo[2] | ((unsigned)lo[3] << 16);
  pl.z = lo[4] | ((unsigned)lo[5] << 16);
  pl.w = lo[6] | ((unsigned)lo[7] << 16);
  *(uint4*)(Ph + (size_t)slot * 8) = ph;
  *(uint4*)(Pl + (size_t)slot * 8) = pl;
}

// ---------------- kv = affine(Wkv @ X) via MFMA : [B][32][N] fp32 ----------------
// 64 pixels/block, 4 waves (wave w -> pixels [16w,16w+16)), XT staged transposed in LDS.
template <int ISBF>
__global__ __launch_bounds__(256, 2) void kv_mfma(
    const void* __restrict__ x, const unsigned short* __restrict__ WkPh,
    const unsigned short* __restrict__ WkPl, const void* __restrict__ kv_scale,
    const void* __restrict__ kv_bias, const int* __restrict__ flag,
    float* __restrict__ kv_out) {
  constexpr int POOL = ISBF ? 32768 : 65536;
  constexpr int XTL_O = 32768;
  __shared__ __align__(16) char pool[POOL];
  if (flag[0] != ISBF) return;
  const int tid = threadIdx.x;
  const int b = blockIdx.x >> 8;
  const int n0 = (blockIdx.x & 255) * 64;
  const int w = tid >> 6, l = tid & 63, g = l >> 4, cc = l & 15;

  // stage XT[p=pixel(64)][c(256)] bf16 hi (+lo fp32 mode)
  {
    const int pq = (tid & 15) * 4;   // 4 pixels
    const int c0 = (tid >> 4) * 16;  // 16 channels
    unsigned short hi[16][4], lo[16][4];
    if (ISBF) {
      const unsigned short* xp =
          (const unsigned short*)x + ((size_t)(b * NC + c0)) * NN + n0 + pq;
#pragma unroll
      for (int i = 0; i < 16; i++) {
        ushort4 r = *(const ushort4*)(xp + (size_t)i * NN);
        hi[i][0] = r.x; hi[i][1] = r.y; hi[i][2] = r.z; hi[i][3] = r.w;
      }
    } else {
      const float* xp = (const float*)x + ((size_t)(b * NC + c0)) * NN + n0 + pq;
#pragma unroll
      for (int i = 0; i < 16; i++) {
        float4 v = *(const float4*)(xp + (size_t)i * NN);
        float vv[4] = {v.x, v.y, v.z, v.w};
#pragma unroll
        for (int j = 0; j < 4; j++) {
          unsigned short hh = f2u(vv[j]);
          hi[i][j] = hh;
          lo[i][j] = f2u(vv[j] - u2f(hh));
        }
      }
    }
#pragma unroll
    for (int j = 0; j < 4; j++) {
      int p = pq + j;
#pragma unroll
      for (int half = 0; half < 2; half++) {
        uint4 wv;
        wv.x = hi[8*half+0][j] | ((unsigned)hi[8*half+1][j] << 16);
        wv.y = hi[8*half+2][j] | ((unsigned)hi[8*half+3][j] << 16);
        wv.z = hi[8*half+4][j] | ((unsigned)hi[8*half+5][j] << 16);
        wv.w = hi[8*half+6][j] | ((unsigned)hi[8*half+7][j] << 16);
        *(uint4*)lds_at(pool, p, c0 * 2 + half * 16) = wv;
        if (!ISBF) {
          uint4 wl2;
          wl2.x = lo[8*half+0][j] | ((unsigned)lo[8*half+1][j] << 16);
          wl2.y = lo[8*half+2][j] | ((unsigned)lo[8*half+3][j] << 16);
          wl2.z = lo[8*half+4][j] | ((unsigned)lo[8*half+5][j] << 16);
          wl2.w = lo[8*half+6][j] | ((unsigned)lo[8*half+7][j] << 16);
          *(uint4*)lds_at(pool + XTL_O, p, c0 * 2 + half * 16) = wl2;
        }
      }
    }
  }
  __syncthreads();

  const f32x4 zero4 = {0.f, 0.f, 0.f, 0.f};
  f32x4 acc[2] = {zero4, zero4};
  const bf16x8* Ah = (const bf16x8*)WkPh;
  const bf16x8* Al = (const bf16x8*)WkPl;
#pragma unroll
  for (int kt = 0; kt < 8; kt++) {
    bf16x8 xb = *(const bf16x8*)lds_at(pool, 16 * w + cc, kt * 64 + 16 * g);
    bf16x8 a0 = Ah[(kt * 2 + 0) * 64 + l];
    bf16x8 a1 = Ah[(kt * 2 + 1) * 64 + l];
    acc[0] = MFMA16(a0, xb, acc[0]);
    acc[1] = MFMA16(a1, xb, acc[1]);
    if (!ISBF) {
      bf16x8 xl = *(const bf16x8*)lds_at(pool + XTL_O, 16 * w + cc, kt * 64 + 16 * g);
      bf16x8 l0 = Al[(kt * 2 + 0) * 64 + l];
      bf16x8 l1 = Al[(kt * 2 + 1) * 64 + l];
      acc[0] = MFMA16(a0, xl, acc[0]);
      acc[0] = MFMA16(l0, xb, acc[0]);
      acc[0] = MFMA16(l0, xl, acc[0]);
      acc[1] = MFMA16(a1, xl, acc[1]);
      acc[1] = MFMA16(l1, xb, acc[1]);
      acc[1] = MFMA16(l1, xl, acc[1]);
    }
  }
  const int n = n0 + 16 * w + cc;
#pragma unroll
  for (int mi = 0; mi < 2; mi++) {
#pragma unroll
    for (int rr = 0; rr < 4; rr++) {
      int d = mi * 16 + 4 * g + rr;
      float v = acc[mi][rr] * ldg(kv_scale, d, ISBF) + ldg(kv_bias, d, ISBF);
      kv_out[((size_t)(b * ND + d)) * NN + n] = v;
    }
  }
}

// ---------------- rowmax over N per (b,d) ----------------
__global__ __launch_bounds__(256) void rowmax_kernel(const float* __restrict__ kv,
                                                     float* __restrict__ m) {
  __shared__ float red[4];
  int row = blockIdx.x;
  const float* p = kv + (size_t)row * NN;
  float mx = -3.0e38f;
  for (int i = threadIdx.x; i < NN; i += 256) mx = fmaxf(mx, p[i]);
  for (int off = 32; off; off >>= 1) mx = fmaxf(mx, __shfl_xor(mx, off, 64));
  if ((threadIdx.x & 63) == 0) red[threadIdx.x >> 6] = mx;
  __syncthreads();
  if (threadIdx.x == 0)
    m[row] = fmaxf(fmaxf(red[0], red[1]), fmaxf(red[2], red[3]));
}

// ---------------- ctx partials via MFMA, no atomics ----------------
// block = (b, 256-px chunk). S[d][e] += E[d][n]*kv[e][n] (3-term hi/lo), Z[d] += E.
__global__ __launch_bounds__(256, 2) void ctx_mfma(const float* __restrict__ kv,
                                                   const float* __restrict__ m,
                                                   float* __restrict__ Spart,
                                                   float* __restrict__ Zpart) {
  constexpr int KH_O = 0, KL_O = 16384, EH_O = 32768, EL_O = 49152;
  __shared__ __align__(16) char pool[65536];
  const int tid = threadIdx.x;
  const int bid = blockIdx.x;
  const int b = bid >> 6;
  const int n0 = (bid & 63) * 256;
  const int r = tid >> 3, q = tid & 7;
  const float mr = m[b * ND + r];
  const float* src = kv + ((size_t)(b * ND + r)) * NN + n0;
  float z = 0.f;
#pragma unroll
  for (int s = 0; s < 8; s++) {
    float4 v = *(const float4*)(src + q * 4 + s * 32);
    float vv[4] = {v.x, v.y, v.z, v.w};
    unsigned short kh[4], kl[4], eh[4], el[4];
#pragma unroll
    for (int j = 0; j < 4; j++) {
      unsigned short hh = f2u(vv[j]);
      kh[j] = hh;
      kl[j] = f2u(vv[j] - u2f(hh));
      float e = __expf(vv[j] - mr);
      z += e;
      unsigned short eH = f2u(e);
      eh[j] = eH;
      el[j] = f2u(e - u2f(eH));
    }
    int colb = 8 * q + 64 * s;
    uint2 a;
    a.x = kh[0] | ((unsigned)kh[1] << 16); a.y = kh[2] | ((unsigned)kh[3] << 16);
    *(uint2*)lds_at(pool + KH_O, r, colb) = a;
    a.x = kl[0] | ((unsigned)kl[1] << 16); a.y = kl[2] | ((unsigned)kl[3] << 16);
    *(uint2*)lds_at(pool + KL_O, r, colb) = a;
    a.x = eh[0] | ((unsigned)eh[1] << 16); a.y = eh[2] | ((unsigned)eh[3] << 16);
    *(uint2*)lds_at(pool + EH_O, r, colb) = a;
    a.x = el[0] | ((unsigned)el[1] << 16); a.y = el[2] | ((unsigned)el[3] << 16);
    *(uint2*)lds_at(pool + EL_O, r, colb) = a;
  }
  z += __shfl_xor(z, 1, 64);
  z += __shfl_xor(z, 2, 64);
  z += __shfl_xor(z, 4, 64);
  if (q == 0) Zpart[(size_t)bid * ND + r] = z;
  __syncthreads();

  const int w = tid >> 6, l = tid & 63, g = l >> 4, cc = l & 15;
  const int mt = w >> 1, nt = w & 1;
  f32x4 sacc = {0.f, 0.f, 0.f, 0.f};
#pragma unroll
  for (int kt = 0; kt < 8; kt++) {
    int colb = kt * 64 + 16 * g;
    bf16x8 ehf = *(const bf16x8*)lds_at(pool + EH_O, 16 * mt + cc, colb);
    bf16x8 elf = *(const bf16x8*)lds_at(pool + EL_O, 16 * mt + cc, colb);
    bf16x8 khf = *(const bf16x8*)lds_at(pool + KH_O, 16 * nt + cc, colb);
    bf16x8 klf = *(const bf16x8*)lds_at(pool + KL_O, 16 * nt + cc, colb);
    sacc = MFMA16(ehf, khf, sacc);
    sacc = MFMA16(ehf, klf, sacc);
    sacc = MFMA16(elf, khf, sacc);
  }
#pragma unroll
  for (int rr = 0; rr < 4; rr++) {
    int row = 16 * mt + 4 * g + rr;
    Spart[(size_t)bid * 1024 + row * 32 + 16 * nt + cc] = sacc[rr];
  }
}

// ---------------- reduce partials + divide -> ctx[b][d][e] ----------------
__global__ __launch_bounds__(256) void ctx_redfin(const float* __restrict__ Spart,
                                                  const float* __restrict__ Zpart,
                                                  float* __restrict__ ctx) {
  int i = blockIdx.x * 256 + threadIdx.x;  // 8192
  int b = i >> 10, cell = i & 1023, d = cell >> 5;
  float s = 0.f, z = 0.f;
  for (int ch = 0; ch < 64; ch++) {
    s += Spart[(size_t)(b * 64 + ch) * 1024 + cell];
    z += Zpart[(size_t)(b * 64 + ch) * ND + d];
  }
  ctx[i] = s / z;
}

// ---------------- fused: q GEMM -> softmax(D) -> ctx matvec -> relu -> out GEMM ----------------
template <int ISBF>
__global__ __launch_bounds__(256, 2) void fused_main(
    const void* __restrict__ x,
    const unsigned short* __restrict__ WqPh, const unsigned short* __restrict__ WqPl,
    const unsigned short* __restrict__ WpPh, const unsigned short* __restrict__ WpPl,
    const void* __restrict__ q_scale, const void* __restrict__ q_bias,
    const void* __restrict__ p_scale, const void* __restrict__ p_bias,
    const float* __restrict__ ctx, const int* __restrict__ flag,
    void* __restrict__ out) {
  constexpr int XT_O = 0;
  constexpr int XTL_O = 16384;                    // fp32 only
  constexpr int SMH_O = ISBF ? 16384 : 32768;
  constexpr int SML_O = ISBF ? 32768 : 49152;
  constexpr int YTH_O = 0;                        // overlays XT
  constexpr int YTL_O = 16384;                    // fp32 only, overlays XTL
  constexpr int OT_O = ISBF ? 16384 : 32768;      // overlays SMH(+part SML)
  constexpr int OT_STR = ISBF ? 88 : 144;
  constexpr int POOL = ISBF ? 49152 : 69632;
  __shared__ __align__(16) char pool[POOL];
  __shared__ float qs_l[NC], qb_l[NC], ps_l[NC], pb_l[NC];
  if (flag[0] != ISBF) return;
  const int tid = threadIdx.x;
  const int b = blockIdx.x >> 9;
  const int n0 = (blockIdx.x & 511) * TILE_P;
  const int w = tid >> 6;
  const int l = tid & 63;
  const int g = l >> 4;
  const int cc = l & 15;
  const f32x4 zero4 = {0.f, 0.f, 0.f, 0.f};

  qs_l[tid] = ldg(q_scale, tid, ISBF);
  qb_l[tid] = ldg(q_bias, tid, ISBF);
  ps_l[tid] = ldg(p_scale, tid, ISBF);
  pb_l[tid] = ldg(p_bias, tid, ISBF);

  // ctx A-fragments: A[m=e][k=d] = ctx[d][e], hi/lo
  bf16x8 cAh[2], cAl[2];
  {
    const float* cb = ctx + (size_t)b * ND * ND;
#pragma unroll
    for (int mp = 0; mp < 2; mp++) {
      bf16x8 ah, al;
#pragma unroll
      for (int el = 0; el < 8; el++) {
        float v = cb[(8 * g + el) * ND + 16 * mp + cc];
        unsigned short hh = f2u(v);
        ah[el] = (short)hh;
        al[el] = (short)f2u(v - u2f(hh));
      }
      cAh[mp] = ah; cAl[mp] = al;
    }
  }

  // ---- stage X tile: XT[p(32)][c(256)] bf16 hi (+lo fp32 mode) ----
  {
    const int c0 = (tid >> 3) * 8;
    const int pq = (tid & 7) * 4;
    unsigned short hi[8][4], lo[8][4];
    if (ISBF) {
      const unsigned short* xp =
          (const unsigned short*)x + ((size_t)(b * NC + c0)) * NN + n0 + pq;
#pragma unroll
      for (int i = 0; i < 8; i++) {
        ushort4 r = *(const ushort4*)(xp + (size_t)i * NN);
        hi[i][0] = r.x; hi[i][1] = r.y; hi[i][2] = r.z; hi[i][3] = r.w;
      }
    } else {
      const float* xp = (const float*)x + ((size_t)(b * NC + c0)) * NN + n0 + pq;
#pragma unroll
      for (int i = 0; i < 8; i++) {
        float4 v = *(const float4*)(xp + (size_t)i * NN);
        float vv[4] = {v.x, v.y, v.z, v.w};
#pragma unroll
        for (int j = 0; j < 4; j++) {
          unsigned short hh = f2u(vv[j]);
          hi[i][j] = hh;
          lo[i][j] = f2u(vv[j] - u2f(hh));
        }
      }
    }
#pragma unroll
    for (int j = 0; j < 4; j++) {
      int p = pq + j;
      uint4 wv;
      wv.x = hi[0][j] | ((unsigned)hi[1][j] << 16);
      wv.y = hi[2][j] | ((unsigned)hi[3][j] << 16);
      wv.z = hi[4][j] | ((unsigned)hi[5][j] << 16);
      wv.w = hi[6][j] | ((unsigned)hi[7][j] << 16);
      *(uint4*)lds_at(pool + XT_O, p, c0 * 2) = wv;
      if (!ISBF) {
        uint4 wl2;
        wl2.x = lo[0][j] | ((unsigned)lo[1][j] << 16);
        wl2.y = lo[2][j] | ((unsigned)lo[3][j] << 16);
        wl2.z = lo[4][j] | ((unsigned)lo[5][j] << 16);
        wl2.w = lo[6][j] | ((unsigned)lo[7][j] << 16);
        *(uint4*)lds_at(pool + XTL_O, p, c0 * 2) = wl2;
      }
    }
  }
  __syncthreads();

  // ---- GEMM1: q = Wq @ x ----
  f32x4 acc[4][2];
#pragma unroll
  for (int mi = 0; mi < 4; mi++) { acc[mi][0] = zero4; acc[mi][1] = zero4; }
  {
    const bf16x8* Aq = (const bf16x8*)WqPh;
    const bf16x8* Aql = (const bf16x8*)WqPl;
#pragma unroll
    for (int kt = 0; kt < 8; kt++) {
      bf16x8 xb0 = *(const bf16x8*)lds_at(pool + XT_O, cc, kt * 64 + 16 * g);
      bf16x8 xb1 = *(const bf16x8*)lds_at(pool + XT_O, 16 + cc, kt * 64 + 16 * g);
      bf16x8 av[4];
#pragma unroll
      for (int mi = 0; mi < 4; mi++) av[mi] = Aq[(kt * 16 + w * 4 + mi) * 64 + l];
#pragma unroll
      for (int mi = 0; mi < 4; mi++) {
        acc[mi][0] = MFMA16(av[mi], xb0, acc[mi][0]);
        acc[mi][1] = MFMA16(av[mi], xb1, acc[mi][1]);
      }
      if (!ISBF) {
        bf16x8 xl0 = *(const bf16x8*)lds_at(pool + XTL_O, cc, kt * 64 + 16 * g);
        bf16x8 xl1 = *(const bf16x8*)lds_at(pool + XTL_O, 16 + cc, kt * 64 + 16 * g);
#pragma unroll
        for (int mi = 0; mi < 4; mi++) {
          bf16x8 al2 = Aql[(kt * 16 + w * 4 + mi) * 64 + l];
          acc[mi][0] = MFMA16(av[mi], xl0, acc[mi][0]);
          acc[mi][1] = MFMA16(av[mi], xl1, acc[mi][1]);
          acc[mi][0] = MFMA16(al2, xb0, acc[mi][0]);
          acc[mi][1] = MFMA16(al2, xb1, acc[mi][1]);
          acc[mi][0] = MFMA16(al2, xl0, acc[mi][0]);
          acc[mi][1] = MFMA16(al2, xl1, acc[mi][1]);
        }
      }
    }
  }

  // ---- softmax over D per (head,pixel); E hi/lo -> SM tiles ----
  float inv_s[2][2];
#pragma unroll
  for (int hp = 0; hp < 2; hp++) {
#pragma unroll
    for (int ni = 0; ni < 2; ni++) {
      float e8[8];
      float mx = -3.0e38f;
#pragma unroll
      for (int mi2 = 0; mi2 < 2; mi2++) {
#pragma unroll
        for (int r = 0; r < 4; r++) {
          int o = w * 64 + (2 * hp + mi2) * 16 + 4 * g + r;
          float v = acc[2 * hp + mi2][ni][r] * qs_l[o] + qb_l[o];
          e8[mi2 * 4 + r] = v;
          mx = fmaxf(mx, v);
        }
      }
      mx = fmaxf(mx, __shfl_xor(mx, 16, 64));
      mx = fmaxf(mx, __shfl_xor(mx, 32, 64));
      float s = 0.f;
#pragma unroll
      for (int i2 = 0; i2 < 8; i2++) { e8[i2] = __expf(e8[i2] - mx); s += e8[i2]; }
      s += __shfl_xor(s, 16, 64);
      s += __shfl_xor(s, 32, 64);
      inv_s[hp][ni] = 1.f / s;
      int p = ni * 16 + cc;
#pragma unroll
      for (int mi2 = 0; mi2 < 2; mi2++) {
        int colb = (w * 64 + (2 * hp + mi2) * 16 + 4 * g) * 2;
        unsigned short h[4], lo2[4];
#pragma unroll
        for (int r = 0; r < 4; r++) {
          float ev = e8[mi2 * 4 + r];
          unsigned short hh = f2u(ev);
          h[r] = hh;
          lo2[r] = f2u(ev - u2f(hh));
        }
        uint2 wh, wl2;
        wh.x = h[0] | ((unsigned)h[1] << 16);
        wh.y = h[2] | ((unsigned)h[3] << 16);
        wl2.x = lo2[0] | ((unsigned)lo2[1] << 16);
        wl2.y = lo2[2] | ((unsigned)lo2[3] << 16);
        *(uint2*)lds_at(pool + SMH_O, p, colb) = wh;
        *(uint2*)lds_at(pool + SML_O, p, colb) = wl2;
      }
    }
  }
  __syncthreads();  // (1) all XT reads done; SM tiles complete

  // ---- ctx GEMM: att = ctx^T @ E, /s, relu, -> YT tiles ----
#pragma unroll
  for (int hp = 0; hp < 2; hp++) {
    f32x4 cacc[2][2];
#pragma unroll
    for (int mp = 0; mp < 2; mp++) { cacc[mp][0] = zero4; cacc[mp][1] = zero4; }
#pragma unroll
    for (int ni = 0; ni < 2; ni++) {
      int p = ni * 16 + cc;
      int colb = ((2 * w + hp) * 32 + 8 * g) * 2;
      bf16x8 bh = *(const bf16x8*)lds_at(pool + SMH_O, p, colb);
      bf16x8 bl = *(const bf16x8*)lds_at(pool + SML_O, p, colb);
#pragma unroll
      for (int mp = 0; mp < 2; mp++) {
        cacc[mp][ni] = MFMA16(cAh[mp], bh, cacc[mp][ni]);
        cacc[mp][ni] = MFMA16(cAh[mp], bl, cacc[mp][ni]);
        cacc[mp][ni] = MFMA16(cAl[mp], bh, cacc[mp][ni]);
        if (!ISBF) cacc[mp][ni] = MFMA16(cAl[mp], bl, cacc[mp][ni]);
      }
    }
#pragma unroll
    for (int mp = 0; mp < 2; mp++) {
#pragma unroll
      for (int ni = 0; ni < 2; ni++) {
        int p = ni * 16 + cc;
        float iv = inv_s[hp][ni];
        unsigned short h[4], lo2[4];
#pragma unroll
        for (int r = 0; r < 4; r++) {
          float y = fmaxf(cacc[mp][ni][r] * iv, 0.f);
          unsigned short hh = f2u(y);
          h[r] = hh;
          lo2[r] = f2u(y - u2f(hh));
        }
        int colb = ((2 * w + hp) * 32 + mp * 16 + 4 * g) * 2;
        uint2 wh;
        wh.x = h[0] | ((unsigned)h[1] << 16);
        wh.y = h[2] | ((unsigned)h[3] << 16);
        *(uint2*)lds_at(pool + YTH_O, p, colb) = wh;
        if (!ISBF) {
          uint2 wl2;
          wl2.x = lo2[0] | ((unsigned)lo2[1] << 16);
          wl2.y = lo2[2] | ((unsigned)lo2[3] << 16);
          *(uint2*)lds_at(pool + YTL_O, p, colb) = wl2;
        }
      }
    }
  }
  __syncthreads();  // (2) YT tiles complete

  // ---- GEMM2: out = Wp @ relu(att) ----
  f32x4 oacc[4][2];
#pragma unroll
  for (int mi = 0; mi < 4; mi++) { oacc[mi][0] = zero4; oacc[mi][1] = zero4; }
  {
    const bf16x8* Ap = (const bf16x8*)WpPh;
    const bf16x8* Apl = (const bf16x8*)WpPl;
#pragma unroll
    for (int kt = 0; kt < 8; kt++) {
      bf16x8 yh0 = *(const bf16x8*)lds_at(pool + YTH_O, cc, kt * 64 + 16 * g);
      bf16x8 yh1 = *(const bf16x8*)lds_at(pool + YTH_O, 16 + cc, kt * 64 + 16 * g);
      bf16x8 av[4];
#pragma unroll
      for (int mi = 0; mi < 4; mi++) av[mi] = Ap[(kt * 16 + w * 4 + mi) * 64 + l];
#pragma unroll
      for (int mi = 0; mi < 4; mi++) {
        oacc[mi][0] = MFMA16(av[mi], yh0, oacc[mi][0]);
        oacc[mi][1] = MFMA16(av[mi], yh1, oacc[mi][1]);
      }
      if (!ISBF) {
        bf16x8 yl0 = *(const bf16x8*)lds_at(pool + YTL_O, cc, kt * 64 + 16 * g);
        bf16x8 yl1 = *(const bf16x8*)lds_at(pool + YTL_O, 16 + cc, kt * 64 + 16 * g);
#pragma unroll
        for (int mi = 0; mi < 4; mi++) {
          bf16x8 al2 = Apl[(kt * 16 + w * 4 + mi) * 64 + l];
          oacc[mi][0] = MFMA16(av[mi], yl0, oacc[mi][0]);
          oacc[mi][1] = MFMA16(av[mi], yl1, oacc[mi][1]);
          oacc[mi][0] = MFMA16(al2, yh0, oacc[mi][0]);
          oacc[mi][1] = MFMA16(al2, yh1, oacc[mi][1]);
        }
      }
    }
  }

  // ---- epilogue: affine -> OT (channel-major) -> coalesced global store ----
  {
    char* OT = pool + OT_O;
#pragma unroll
    for (int mi = 0; mi < 4; mi++) {
#pragma unroll
      for (int ni = 0; ni < 2; ni++) {
#pragma unroll
        for (int r = 0; r < 4; r++) {
          int o = w * 64 + mi * 16 + 4 * g + r;
          float v = oacc[mi][ni][r] * ps_l[o] + pb_l[o];
          int p = ni * 16 + cc;
          if (ISBF)
            *(unsigned short*)(OT + o * OT_STR + p * 2) = f2u(v);
          else
            *(float*)(OT + o * OT_STR + p * 4) = v;
        }
      }
    }
  }
  __syncthreads();  // (3) OT complete
  {
    char* OT = pool + OT_O;
    int o = tid;
    size_t gbase = ((size_t)(b * NC + o)) * NN + n0;
    if (ISBF) {
      unsigned short* po = (unsigned short*)out + gbase;
#pragma unroll
      for (int k = 0; k < 4; k++) {
        uint2 a = *(const uint2*)(OT + o * OT_STR + k * 16);
        uint2 b2 = *(const uint2*)(OT + o * OT_STR + k * 16 + 8);
        uint4 pk = make_uint4(a.x, a.y, b2.x, b2.y);
        *(uint4*)(po + k * 8) = pk;
      }
    } else {
      float* po = (float*)out + gbase;
#pragma unroll
      for (int k = 0; k < 8; k++)
        *(float4*)(po + k * 4) = *(const float4*)(OT + o * OT_STR + k * 16);
    }
  }
}

extern "C" void kernel_launch(void* const* d_in, const int* in_sizes, int n_in,
                              void* d_out, int out_size, void* d_ws, size_t ws_size,
                              hipStream_t stream) {
  const void* input   = d_in[0];
  const void* wq      = d_in[1];
  const void* q_scale = d_in[2];
  const void* q_bias  = d_in[3];
  const void* wkv     = d_in[4];
  const void* kv_scale= d_in[5];
  const void* kv_bias = d_in[6];
  const void* wp      = d_in[7];
  const void* p_scale = d_in[8];
  const void* p_bias  = d_in[9];

  char* w = (char*)d_ws;
  int*  flag = (int*)w;      w += 256;
  float* kv   = (float*)w;   w += (size_t)NB * ND * NN * 4;        // 16 MiB
  float* mrow = (float*)w;   w += 1024;
  float* Spart = (float*)w;  w += (size_t)512 * 1024 * 4;          // 2 MiB
  float* Zpart = (float*)w;  w += (size_t)512 * ND * 4;            // 64 KiB
  float* ctx  = (float*)w;   w += (size_t)NB * ND * ND * 4;        // 32 KiB
  unsigned short* WqPh = (unsigned short*)w; w += (size_t)NC * NC * 2;
  unsigned short* WqPl = (unsigned short*)w; w += (size_t)NC * NC * 2;
  unsigned short* WpPh = (unsigned short*)w; w += (size_t)NC * NC * 2;
  unsigned short* WpPl = (unsigned short*)w; w += (size_t)NC * NC * 2;
  unsigned short* WkPh = (unsigned short*)w; w += (size_t)ND * NC * 2;
  unsigned short* WkPl = (unsigned short*)w; w += (size_t)ND * NC * 2;

  detect_kernel<<<1, 256, 0, stream>>>(input, flag);
  prep_weights<<<68, 256, 0, stream>>>(wq, wp, wkv, flag, WqPh, WqPl, WpPh, WpPl,
                                       WkPh, WkPl);
  kv_mfma<1><<<2048, 256, 0, stream>>>(input, WkPh, WkPl, kv_scale, kv_bias, flag, kv);
  kv_mfma<0><<<2048, 256, 0, stream>>>(input, WkPh, WkPl, kv_scale, kv_bias, flag, kv);
  rowmax_kernel<<<256, 256, 0, stream>>>(kv, mrow);
  ctx_mfma<<<512, 256, 0, stream>>>(kv, mrow, Spart, Zpart);
  ctx_redfin<<<32, 256, 0, stream>>>(Spart, Zpart, ctx);
  fused_main<1><<<4096, 256, 0, stream>>>(input, WqPh, WqPl, WpPh, WpPl,
                                          q_scale, q_bias, p_scale, p_bias,
                                          ctx, flag, (void*)d_out);
  fused_main<0><<<4096, 256, 0, stream>>>(input, WqPh, WqPl, WpPh, WpPl,
                                          q_scale, q_bias, p_scale, p_bias,
                                          ctx, flag, (void*)d_out);
}